// Round 1
// baseline (97.738 us; speedup 1.0000x reference)
//
#include <hip/hip_runtime.h>

// ECT: nh = x @ v  ->  bin  ->  histogram over (batch, bin, theta)  ->  cumsum over bin axis.
// batch is SORTED, so each block binary-searches its batch's point range and owns an
// exclusive (batch, theta-slice) region of the output: no global atomics, no workspace.

constexpr int N_PTS   = 200000;
constexpr int T       = 128;   // num_thetas
constexpr int R       = 128;   // resolution
constexpr int B       = 64;    // batch_size
constexpr int SPLIT_T = 4;     // theta slices per batch
constexpr int TT      = T / SPLIT_T;        // 32 thetas per block
constexpr int NTHREADS = 1024;              // 16 waves/CU (grid = 256 = 1 block/CU)
constexpr int PPI     = NTHREADS / TT;      // 32 points in flight per block-iteration
constexpr int RCH     = R / PPI;            // 4 resolution rows per thread in epilogue

__device__ __forceinline__ int lower_bound_i32(const int* __restrict__ a, int n, int val) {
    int lo = 0, hi = n;
    while (lo < hi) {
        int mid = (lo + hi) >> 1;
        if (a[mid] < val) lo = mid + 1; else hi = mid;
    }
    return lo;
}

__global__ __launch_bounds__(NTHREADS)
void FastEctLayer_73065983639654_kernel(const float* __restrict__ x,
                                        const float* __restrict__ v,
                                        const int*   __restrict__ batch,
                                        float*       __restrict__ out) {
    // hist[r][tl]: bank = tl % 32 -> 2-way wave aliasing only (free on gfx950)
    __shared__ unsigned int hist[R * TT];       // 16 KiB
    __shared__ unsigned int partial[PPI * TT];  // 4 KiB

    const int tid    = threadIdx.x;
    const int tl     = tid & (TT - 1);          // theta within slice
    const int sub    = tid / TT;                // 0..31 point sub-lane
    const int bat    = blockIdx.x / SPLIT_T;
    const int theta0 = (blockIdx.x % SPLIT_T) * TT;

    for (int i = tid; i < R * TT; i += NTHREADS) hist[i] = 0u;

    // direction vector for this thread's theta, kept in registers
    const float v0 = v[0 * T + theta0 + tl];
    const float v1 = v[1 * T + theta0 + tl];
    const float v2 = v[2 * T + theta0 + tl];

    // batch is sorted: locate [start, end) for this block's batch (uniform across threads)
    const int start = lower_bound_i32(batch, N_PTS, bat);
    const int end   = lower_bound_i32(batch, N_PTS, bat + 1);

    __syncthreads();

    // main loop: 32 points in flight; 32 lanes broadcast-read each point's coords
    for (int p = start + sub; p < end; p += PPI) {
        const float x0 = x[p * 3 + 0];
        const float x1 = x[p * 3 + 1];
        const float x2 = x[p * 3 + 2];
        const float nh = fmaf(x0, v0, fmaf(x1, v1, x2 * v2));
        // match reference: floor((nh + 1) * (0.5*R)), clip to [0, R-1]
        int bin = (int)floorf((nh + 1.0f) * (0.5f * (float)R));
        bin = min(max(bin, 0), R - 1);
        atomicAdd(&hist[bin * TT + tl], 1u);    // ds_atomic_add_u32, no return
    }

    __syncthreads();

    // cumsum over r (two-phase chunked scan), direct store to out[bat][r][theta0+tl]
    const int r0 = sub * RCH;
    unsigned int csum = 0;
#pragma unroll
    for (int r = r0; r < r0 + RCH; ++r) csum += hist[r * TT + tl];
    partial[sub * TT + tl] = csum;
    __syncthreads();

    unsigned int run = 0;
    for (int s = 0; s < sub; ++s) run += partial[s * TT + tl];
#pragma unroll
    for (int r = r0; r < r0 + RCH; ++r) {
        run += hist[r * TT + tl];
        out[((size_t)bat * R + r) * T + theta0 + tl] = (float)run;  // counts <= ~3.4K: exact in f32
    }
}

extern "C" void kernel_launch(void* const* d_in, const int* in_sizes, int n_in,
                              void* d_out, int out_size, void* d_ws, size_t ws_size,
                              hipStream_t stream) {
    const float* x     = (const float*)d_in[0];
    const float* v     = (const float*)d_in[1];
    const int*   batch = (const int*)d_in[2];
    float*       out   = (float*)d_out;
    // inputs 3 (resolution=128) and 4 (batch_size=64) are compile-time constants here

    dim3 grid(B * SPLIT_T);   // 256 blocks = 1 per CU
    dim3 block(NTHREADS);
    hipLaunchKernelGGL(FastEctLayer_73065983639654_kernel, grid, block, 0, stream,
                       x, v, batch, out);
}

// Round 2
// 82.006 us; speedup vs baseline: 1.1918x; 1.1918x over previous
//
#include <hip/hip_runtime.h>

// ECT: nh = x @ v  ->  bin  ->  histogram over (batch, bin, theta)  ->  cumsum over bin axis.
// batch is SORTED: each block binary-searches its batch's point range and owns an
// exclusive (batch, theta-slice) region of the output: no global atomics, no workspace.
//
// R1: latency-bound (VALUBusy 20%, HBM 2.7%). Fix: unroll point loop 8x with a
// separated load phase so ~24 global loads are in flight per thread.

constexpr int N_PTS   = 200000;
constexpr int T       = 128;   // num_thetas
constexpr int R       = 128;   // resolution
constexpr int B       = 64;    // batch_size
constexpr int SPLIT_T = 4;     // theta slices per batch
constexpr int TT      = T / SPLIT_T;        // 32 thetas per block
constexpr int NTHREADS = 1024;              // 16 waves/CU (grid = 256 = 1 block/CU)
constexpr int PPI     = NTHREADS / TT;      // 32 points in flight per block-iteration
constexpr int RCH     = R / PPI;            // 4 resolution rows per thread in epilogue
constexpr int UNROLL  = 8;                  // points per thread per unrolled iteration

__device__ __forceinline__ int lower_bound_i32(const int* __restrict__ a, int n, int val) {
    int lo = 0, hi = n;
    while (lo < hi) {
        int mid = (lo + hi) >> 1;
        if (a[mid] < val) lo = mid + 1; else hi = mid;
    }
    return lo;
}

__global__ __launch_bounds__(NTHREADS)
void FastEctLayer_73065983639654_kernel(const float* __restrict__ x,
                                        const float* __restrict__ v,
                                        const int*   __restrict__ batch,
                                        float*       __restrict__ out) {
    // hist[r][tl]: bank = tl % 32 -> 2-way wave aliasing only (free on gfx950)
    __shared__ unsigned int hist[R * TT];       // 16 KiB
    __shared__ unsigned int partial[PPI * TT];  // 4 KiB

    const int tid    = threadIdx.x;
    const int tl     = tid & (TT - 1);          // theta within slice
    const int sub    = tid / TT;                // 0..31 point sub-lane
    const int bat    = blockIdx.x / SPLIT_T;
    const int theta0 = (blockIdx.x % SPLIT_T) * TT;

    for (int i = tid; i < R * TT; i += NTHREADS) hist[i] = 0u;

    // direction vector for this thread's theta, kept in registers
    const float v0 = v[0 * T + theta0 + tl];
    const float v1 = v[1 * T + theta0 + tl];
    const float v2 = v[2 * T + theta0 + tl];

    // batch is sorted: locate [start, end) for this block's batch (uniform across threads)
    const int start = lower_bound_i32(batch, N_PTS, bat);
    const int end   = lower_bound_i32(batch, N_PTS, bat + 1);

    __syncthreads();

    // ---- main loop: UNROLL points per thread in flight; load phase fully
    // separated from compute phase so the compiler batches global_load_dword
    // and staggers s_waitcnt vmcnt(N) instead of draining per point. ----
    int p = start + sub;
    for (; p + (UNROLL - 1) * PPI < end; p += UNROLL * PPI) {
        float c0[UNROLL], c1[UNROLL], c2[UNROLL];
#pragma unroll
        for (int u = 0; u < UNROLL; ++u) {
            const int q = p + u * PPI;
            c0[u] = x[q * 3 + 0];
            c1[u] = x[q * 3 + 1];
            c2[u] = x[q * 3 + 2];
        }
#pragma unroll
        for (int u = 0; u < UNROLL; ++u) {
            const float nh = fmaf(c0[u], v0, fmaf(c1[u], v1, c2[u] * v2));
            int bin = (int)floorf(fmaf(nh, 0.5f * (float)R, 0.5f * (float)R));
            bin = min(max(bin, 0), R - 1);
            atomicAdd(&hist[bin * TT + tl], 1u);    // ds_add_u32 (no return)
        }
    }
    for (; p < end; p += PPI) {
        const float nh = fmaf(x[p * 3 + 0], v0, fmaf(x[p * 3 + 1], v1, x[p * 3 + 2] * v2));
        int bin = (int)floorf(fmaf(nh, 0.5f * (float)R, 0.5f * (float)R));
        bin = min(max(bin, 0), R - 1);
        atomicAdd(&hist[bin * TT + tl], 1u);
    }

    __syncthreads();

    // cumsum over r (two-phase chunked scan), direct store to out[bat][r][theta0+tl]
    const int r0 = sub * RCH;
    unsigned int csum = 0;
#pragma unroll
    for (int r = r0; r < r0 + RCH; ++r) csum += hist[r * TT + tl];
    partial[sub * TT + tl] = csum;
    __syncthreads();

    unsigned int run = 0;
    for (int s = 0; s < sub; ++s) run += partial[s * TT + tl];
#pragma unroll
    for (int r = r0; r < r0 + RCH; ++r) {
        run += hist[r * TT + tl];
        out[((size_t)bat * R + r) * T + theta0 + tl] = (float)run;  // counts <= ~3.4K: exact in f32
    }
}

extern "C" void kernel_launch(void* const* d_in, const int* in_sizes, int n_in,
                              void* d_out, int out_size, void* d_ws, size_t ws_size,
                              hipStream_t stream) {
    const float* x     = (const float*)d_in[0];
    const float* v     = (const float*)d_in[1];
    const int*   batch = (const int*)d_in[2];
    float*       out   = (float*)d_out;

    dim3 grid(B * SPLIT_T);   // 256 blocks = 1 per CU
    dim3 block(NTHREADS);
    hipLaunchKernelGGL(FastEctLayer_73065983639654_kernel, grid, block, 0, stream,
                       x, v, batch, out);
}

// Round 3
// 77.322 us; speedup vs baseline: 1.2640x; 1.0606x over previous
//
#include <hip/hip_runtime.h>

// ECT: nh = x @ v  ->  bin  ->  histogram over (batch, bin, theta)  ->  cumsum over bin axis.
// batch is SORTED: each block binary-searches its batch's point range and owns an
// exclusive (batch, theta-slice) region of the output: no global atomics, no workspace.
//
// R1: latency-bound (VALUBusy 20%, HBM 2.7%) -> 8x unroll. 42 -> ~26 us.
// R2 theory: VMEM issue-bound: 32-way broadcast point loads = 4700 wave-loads/CU.
// Fix: each thread owns 4 thetas (8 theta-groups x 128 point-lanes), cutting loads 4x.
// LDS banking: diagonal theta assignment tl_j = (4*tg + j + pl) % 32 gives exactly
// 2 lanes/bank per atomic instruction (2-way = free, m136), while (tg,j) -> 4tg+j
// stays a bijection so each point's 32 thetas are covered exactly once.

constexpr int N_PTS    = 200000;
constexpr int T        = 128;   // num_thetas
constexpr int R        = 128;   // resolution
constexpr int B        = 64;    // batch_size
constexpr int SPLIT_T  = 4;     // theta slices per batch
constexpr int TT       = T / SPLIT_T;       // 32 thetas per block
constexpr int NTHREADS = 1024;
constexpr int TG       = 8;                 // theta-groups per block (4 thetas each)
constexpr int PL       = NTHREADS / TG;     // 128 point-lanes per block
constexpr int UNROLL   = 4;                 // points per thread in flight
constexpr int SUBS     = NTHREADS / TT;     // 32 (epilogue partitioning)
constexpr int RCH      = R / SUBS;          // 4 resolution rows per thread in epilogue

__device__ __forceinline__ int lower_bound_i32(const int* __restrict__ a, int n, int val) {
    int lo = 0, hi = n;
    while (lo < hi) {
        int mid = (lo + hi) >> 1;
        if (a[mid] < val) lo = mid + 1; else hi = mid;
    }
    return lo;
}

__global__ __launch_bounds__(NTHREADS)
void FastEctLayer_73065983639654_kernel(const float* __restrict__ x,
                                        const float* __restrict__ v,
                                        const int*   __restrict__ batch,
                                        float*       __restrict__ out) {
    __shared__ unsigned int hist[R * TT];        // 16 KiB, layout [bin][tl]
    __shared__ unsigned int partial[SUBS * TT];  // 4 KiB

    const int tid    = threadIdx.x;
    const int tg     = tid & (TG - 1);           // theta-group 0..7
    const int pl     = tid >> 3;                 // point-lane 0..127 (wave = 8 pl x 8 tg)
    const int bat    = blockIdx.x / SPLIT_T;
    const int theta0 = (blockIdx.x % SPLIT_T) * TT;

    for (int i = tid; i < R * TT; i += NTHREADS) hist[i] = 0u;

    // this thread's 4 thetas (diagonalized for conflict-free atomics)
    int   tlj[4];
    float vv0[4], vv1[4], vv2[4];
#pragma unroll
    for (int j = 0; j < 4; ++j) {
        const int tl = (4 * tg + j + pl) & (TT - 1);
        tlj[j] = tl;
        vv0[j] = v[0 * T + theta0 + tl];
        vv1[j] = v[1 * T + theta0 + tl];
        vv2[j] = v[2 * T + theta0 + tl];
    }

    // batch is sorted: locate [start, end) for this block's batch (uniform across threads)
    const int start = lower_bound_i32(batch, N_PTS, bat);
    const int end   = lower_bound_i32(batch, N_PTS, bat + 1);

    __syncthreads();

    // main loop: UNROLL points per thread in flight, loads separated from compute
    int p = start + pl;
    for (; p + (UNROLL - 1) * PL < end; p += UNROLL * PL) {
        float c0[UNROLL], c1[UNROLL], c2[UNROLL];
#pragma unroll
        for (int u = 0; u < UNROLL; ++u) {
            const int q = p + u * PL;
            c0[u] = x[q * 3 + 0];
            c1[u] = x[q * 3 + 1];
            c2[u] = x[q * 3 + 2];
        }
#pragma unroll
        for (int u = 0; u < UNROLL; ++u) {
#pragma unroll
            for (int j = 0; j < 4; ++j) {
                const float nh = fmaf(c0[u], vv0[j], fmaf(c1[u], vv1[j], c2[u] * vv2[j]));
                // trunc instead of floor is safe: negatives clamp to 0 anyway
                int bin = (int)fmaf(nh, 0.5f * (float)R, 0.5f * (float)R);
                bin = min(max(bin, 0), R - 1);
                atomicAdd(&hist[bin * TT + tlj[j]], 1u);   // 2-way banked: free
            }
        }
    }
    for (; p < end; p += PL) {
        const float x0 = x[p * 3 + 0], x1 = x[p * 3 + 1], x2 = x[p * 3 + 2];
#pragma unroll
        for (int j = 0; j < 4; ++j) {
            const float nh = fmaf(x0, vv0[j], fmaf(x1, vv1[j], x2 * vv2[j]));
            int bin = (int)fmaf(nh, 0.5f * (float)R, 0.5f * (float)R);
            bin = min(max(bin, 0), R - 1);
            atomicAdd(&hist[bin * TT + tlj[j]], 1u);
        }
    }

    __syncthreads();

    // cumsum over r (two-phase chunked scan), direct store to out[bat][r][theta0+tl]
    const int tl  = tid & (TT - 1);
    const int sub = tid / TT;
    const int r0  = sub * RCH;
    unsigned int csum = 0;
#pragma unroll
    for (int r = r0; r < r0 + RCH; ++r) csum += hist[r * TT + tl];
    partial[sub * TT + tl] = csum;
    __syncthreads();

    unsigned int run = 0;
    for (int s = 0; s < sub; ++s) run += partial[s * TT + tl];
#pragma unroll
    for (int r = r0; r < r0 + RCH; ++r) {
        run += hist[r * TT + tl];
        out[((size_t)bat * R + r) * T + theta0 + tl] = (float)run;  // counts <= ~3.4K: exact in f32
    }
}

extern "C" void kernel_launch(void* const* d_in, const int* in_sizes, int n_in,
                              void* d_out, int out_size, void* d_ws, size_t ws_size,
                              hipStream_t stream) {
    const float* x     = (const float*)d_in[0];
    const float* v     = (const float*)d_in[1];
    const int*   batch = (const int*)d_in[2];
    float*       out   = (float*)d_out;

    dim3 grid(B * SPLIT_T);   // 256 blocks = 1 per CU
    dim3 block(NTHREADS);
    hipLaunchKernelGGL(FastEctLayer_73065983639654_kernel, grid, block, 0, stream,
                       x, v, batch, out);
}

// Round 4
// 71.816 us; speedup vs baseline: 1.3610x; 1.0767x over previous
//
#include <hip/hip_runtime.h>

// ECT: nh = x @ v -> bin -> histogram over (batch, bin, theta) -> cumsum over bins.
// batch is SORTED: each block owns (batch, 32-theta slice) exclusively; no global
// atomics, no workspace.
//
// R1: 8x unroll (latency)            42 -> ~26 us
// R2: 4 thetas/thread (VMEM issue)   ~26 -> ~21 us
// R3: float4 chunk loads (3 loads / 4 points) + 64-ary cooperative ballot search
//     (3 dependent probe rounds instead of 18, waves 0/1 only).
// LDS banking: tl_j = (4*tg + j + pl) % 32 -> exactly 2 lanes/bank per atomic
// (2-way = free, m136); (tg,j)->4tg+j bijective so all 32 thetas covered.

constexpr int N_PTS    = 200000;
constexpr int T        = 128;   // num_thetas
constexpr int R        = 128;   // resolution
constexpr int B        = 64;    // batch_size
constexpr int SPLIT_T  = 4;     // theta slices per batch
constexpr int TT       = T / SPLIT_T;       // 32 thetas per block
constexpr int NTHREADS = 1024;
constexpr int TG       = 8;                 // theta-groups per block (4 thetas each)
constexpr int PL       = NTHREADS / TG;     // 128 point-lanes (chunk lanes) per block
constexpr int SUBS     = NTHREADS / TT;     // 32 (epilogue partitioning)
constexpr int RCH      = R / SUBS;          // 4 resolution rows per thread in epilogue

__global__ __launch_bounds__(NTHREADS)
void FastEctLayer_73065983639654_kernel(const float* __restrict__ x,
                                        const float* __restrict__ v,
                                        const int*   __restrict__ batch,
                                        float*       __restrict__ out) {
    __shared__ unsigned int hist[R * TT];        // 16 KiB, layout [bin][tl]
    __shared__ unsigned int partial[SUBS * TT];  // 4 KiB
    __shared__ int s_range[2];

    const int tid    = threadIdx.x;
    const int tg     = tid & (TG - 1);           // theta-group 0..7
    const int pl     = tid >> 3;                 // chunk-lane 0..127
    const int bat    = blockIdx.x / SPLIT_T;
    const int theta0 = (blockIdx.x % SPLIT_T) * TT;

    for (int i = tid; i < R * TT; i += NTHREADS) hist[i] = 0u;

    // ---- 64-ary cooperative lower_bound: 200000 -> 3125 -> 49 -> 1 (3 probe
    // rounds, each one dependent global load + ballot). wave 0 -> start, wave 1 -> end.
    const int wave = tid >> 6, lane = tid & 63;
    if (wave < 2) {
        const int val = bat + wave;
        int lo = 0, hi = N_PTS;
        while (lo < hi) {
            const int step = (hi - lo + 63) >> 6;
            const int pos  = lo + lane * step;
            const bool pred = (pos < hi) && (batch[pos] < val);
            const unsigned long long m = __ballot(pred);
            const int k = __popcll(m);
            if (k == 0) {
                hi = lo;                          // batch[lo] >= val -> done
            } else {
                const int nlo = lo + (k - 1) * step + 1;  // batch[lo+(k-1)step] < val
                hi = min(hi, lo + k * step);              // batch[lo+k*step] >= val (if valid)
                lo = nlo;
            }
        }
        if (lane == 0) s_range[wave] = lo;
    }

    // this thread's 4 thetas (diagonalized for conflict-free atomics)
    int   tlj[4];
    float vv0[4], vv1[4], vv2[4];
#pragma unroll
    for (int j = 0; j < 4; ++j) {
        const int tl = (4 * tg + j + pl) & (TT - 1);
        tlj[j] = tl;
        vv0[j] = v[0 * T + theta0 + tl];
        vv1[j] = v[1 * T + theta0 + tl];
        vv2[j] = v[2 * T + theta0 + tl];
    }

    __syncthreads();
    const int start = s_range[0];
    const int end   = s_range[1];

    // chunk-of-4 points, 16B-aligned: a0 = start rounded down to x4. Chunks may
    // cover up to 2 points past `end`; those belong to the next batch and are
    // predicated out. In-bounds proof: for end < N, end+2 < N (last batch has
    // ~3000 points); for end == N, (end - a0) % 4 == 0 so chunks land exactly.
    const int a0      = start & ~3;
    const int nchunks = (end - a0 + 3) >> 2;
    const float4* __restrict__ X4 = (const float4*)x;
    const int cbase = (a0 >> 2) * 3;             // float4 index of chunk 0

    auto process4 = [&](int pbase, float4 f0, float4 f1, float4 f2) {
        const float px[4] = {f0.x, f0.w, f1.z, f2.y};
        const float py[4] = {f0.y, f1.x, f1.w, f2.z};
        const float pz[4] = {f0.z, f1.y, f2.x, f2.w};
        if (pbase >= start && pbase + 3 < end) {
            // fast path: whole chunk in range
#pragma unroll
            for (int i = 0; i < 4; ++i) {
#pragma unroll
                for (int j = 0; j < 4; ++j) {
                    const float nh = fmaf(px[i], vv0[j], fmaf(py[i], vv1[j], pz[i] * vv2[j]));
                    int bin = (int)fmaf(nh, 0.5f * (float)R, 0.5f * (float)R);
                    bin = min(max(bin, 0), R - 1);
                    atomicAdd(&hist[bin * TT + tlj[j]], 1u);   // 2-way banked: free
                }
            }
        } else {
#pragma unroll
            for (int i = 0; i < 4; ++i) {
                const int p = pbase + i;
                if (p >= start && p < end) {
#pragma unroll
                    for (int j = 0; j < 4; ++j) {
                        const float nh = fmaf(px[i], vv0[j], fmaf(py[i], vv1[j], pz[i] * vv2[j]));
                        int bin = (int)fmaf(nh, 0.5f * (float)R, 0.5f * (float)R);
                        bin = min(max(bin, 0), R - 1);
                        atomicAdd(&hist[bin * TT + tlj[j]], 1u);
                    }
                }
            }
        }
    };

    // main loop: 2 chunks (8 points) in flight, 6 float4 loads per iteration
    int c = pl;
    for (; c + PL < nchunks; c += 2 * PL) {
        const int c2 = c + PL;
        const float4 fa0 = X4[cbase + 3 * c],  fa1 = X4[cbase + 3 * c + 1],  fa2 = X4[cbase + 3 * c + 2];
        const float4 fb0 = X4[cbase + 3 * c2], fb1 = X4[cbase + 3 * c2 + 1], fb2 = X4[cbase + 3 * c2 + 2];
        process4(a0 + 4 * c,  fa0, fa1, fa2);
        process4(a0 + 4 * c2, fb0, fb1, fb2);
    }
    for (; c < nchunks; c += PL) {
        const float4 f0 = X4[cbase + 3 * c], f1 = X4[cbase + 3 * c + 1], f2 = X4[cbase + 3 * c + 2];
        process4(a0 + 4 * c, f0, f1, f2);
    }

    __syncthreads();

    // cumsum over r (two-phase chunked scan), direct store to out[bat][r][theta0+tl]
    const int tl  = tid & (TT - 1);
    const int sub = tid / TT;
    const int r0  = sub * RCH;
    unsigned int csum = 0;
#pragma unroll
    for (int r = r0; r < r0 + RCH; ++r) csum += hist[r * TT + tl];
    partial[sub * TT + tl] = csum;
    __syncthreads();

    unsigned int run = 0;
    for (int s = 0; s < sub; ++s) run += partial[s * TT + tl];
#pragma unroll
    for (int r = r0; r < r0 + RCH; ++r) {
        run += hist[r * TT + tl];
        out[((size_t)bat * R + r) * T + theta0 + tl] = (float)run;  // counts <= ~3.4K: exact in f32
    }
}

extern "C" void kernel_launch(void* const* d_in, const int* in_sizes, int n_in,
                              void* d_out, int out_size, void* d_ws, size_t ws_size,
                              hipStream_t stream) {
    const float* x     = (const float*)d_in[0];
    const float* v     = (const float*)d_in[1];
    const int*   batch = (const int*)d_in[2];
    float*       out   = (float*)d_out;

    dim3 grid(B * SPLIT_T);   // 256 blocks = 1 per CU
    dim3 block(NTHREADS);
    hipLaunchKernelGGL(FastEctLayer_73065983639654_kernel, grid, block, 0, stream,
                       x, v, batch, out);
}